// Round 4
// baseline (1894.923 us; speedup 1.0000x reference)
//
#include <hip/hip_runtime.h>
#include <cstdint>

// B=4, S=2048, d=2048, dff=8192. Inputs fp32, output fp32.
// All GEMMs bf16 MFMA (fp32 accum). Weights pre-converted fp32->bf16 per phase.
//
// ws (112 MiB): w0[0,32) x1 -> h2 | w1[32,64) Vt -> f1
//               w2[64,96) Wqkv_bf(24) -> attn(32) | w3[96,112) scP(8,bf16) -> Wo_bf(8) -> W1c(8)+W2c(8)
// d_out (64 MiB fp32): Q bf16 [0,32MiB) + K bf16 [32,64MiB) until PROJ, then src2 fp32 (in-place final).
//
// gemm256 (QKV/PROJ/FFN1/F2A): 256x128 tile, BK=32, 256 threads = 4 waves
// (2Mx2N, each 128x64 out), double-buffered 48 KiB LDS -> 2 BLOCKS/CU.
// Rationale (R3 post-mortem): with 250 regs/thread the chip caps at 8 waves/CU;
// a single 512-thread block makes all 8 barrier-locked (every wait globalizes,
// MfmaUtil pinned ~33% across 3 schedule variants). Two 4-wave blocks keep the
// same 8 waves but in two barrier-independent groups -> cross-block overlap
// fills the matrix pipe during the other block's lgkm/vmcnt/barrier waits.

typedef __attribute__((ext_vector_type(8))) short short8;
typedef __attribute__((ext_vector_type(4))) float floatx4;

#define PLANE 16777216L   // 8192*2048 (Q->K plane stride, elements)
#define SS    4194304L    // 2048*2048 (per-batch matrix, elements)

__device__ __forceinline__ float bf2f(unsigned short u) {
    union { unsigned int i; float f; } v; v.i = ((unsigned int)u) << 16; return v.f;
}
__device__ __forceinline__ unsigned short f2bf(float f) {
    union { float f; unsigned int i; } v; v.f = f;
    unsigned int x = v.i;
    return (unsigned short)((x + 0x7FFFu + ((x >> 16) & 1u)) >> 16);
}
__device__ __forceinline__ uint4 pack8(float4 a, float4 b) {
    unsigned short o[8];
    o[0] = f2bf(a.x); o[1] = f2bf(a.y); o[2] = f2bf(a.z); o[3] = f2bf(a.w);
    o[4] = f2bf(b.x); o[5] = f2bf(b.y); o[6] = f2bf(b.z); o[7] = f2bf(b.w);
    return *(uint4*)o;
}
// async global->LDS, 16B per lane; LDS dest = wave-uniform base + lane*16
__device__ __forceinline__ void gl_lds16(const void* g, void* l) {
    __builtin_amdgcn_global_load_lds(
        (const __attribute__((address_space(1))) void*)g,
        (__attribute__((address_space(3))) void*)l, 16, 0, 0);
}

#define EM_QKV  0
#define EM_SC   1
#define EM_PV   2
#define EM_PROJ 3
#define EM_FFN1 4
#define EM_F2A  5

// ---------------------------------------------------------------------------
// Legacy 128x128 kernel — kept for the causal attention GEMMs (SC, PV).
// ---------------------------------------------------------------------------
template<int EM>
__launch_bounds__(256, 2)
__global__ void gemm_bt(const unsigned short* __restrict__ A,
                        const unsigned short* __restrict__ B,
                        void* __restrict__ Cv, int N, int K,
                        const float* __restrict__ bias,
                        const unsigned short* __restrict__ resid16,
                        unsigned short* __restrict__ outQ,
                        unsigned short* __restrict__ outVt)
{
    constexpr int BM = 128, BN = 128, BK = 32;
    __shared__ __align__(16) unsigned short As[BM * BK];
    __shared__ __align__(16) unsigned short Bs[BN * BK];

    const int m0 = blockIdx.x * BM, n0 = blockIdx.y * BN;
    if (EM == EM_SC && n0 > m0 + (BM - 1)) return;   // fully-masked causal tile

    int kmax = K;
    if (EM == EM_PV) { kmax = m0 + BM; if (kmax > K) kmax = K; }  // P zero past causal edge
    const int nsteps = kmax / BK;

    const int t = threadIdx.x;
    const int lane = t & 63, wave = t >> 6;
    const int q = lane >> 4, ln = lane & 15;
    const int wm = (wave >> 1) * 64, wn = (wave & 1) * 64;

    const int r0 = wave * 32;
    const int rA = r0 + (lane >> 2);
    const int cslot = lane & 3;
    const int cg0 = (cslot ^ (rA & 3)) * 8;
    const int cg1 = (cslot ^ ((rA + 16) & 3)) * 8;
    const unsigned short* Agp0 = A + (long)(m0 + rA) * K + cg0;
    const unsigned short* Agp1 = A + (long)(m0 + rA + 16) * K + cg1;
    const unsigned short* Bgp0 = B + (long)(n0 + rA) * K + cg0;
    const unsigned short* Bgp1 = B + (long)(n0 + rA + 16) * K + cg1;
    unsigned short* lA0 = &As[r0 * 32];
    unsigned short* lA1 = &As[(r0 + 16) * 32];
    unsigned short* lB0 = &Bs[r0 * 32];
    unsigned short* lB1 = &Bs[(r0 + 16) * 32];

    floatx4 acc[4][4];
#pragma unroll
    for (int i = 0; i < 4; ++i)
#pragma unroll
        for (int j = 0; j < 4; ++j) acc[i][j] = (floatx4){0.f, 0.f, 0.f, 0.f};

    for (int s = 0; s < nsteps; ++s) {
        const long off = (long)s * BK;
        __syncthreads();
        gl_lds16(Agp0 + off, lA0);
        gl_lds16(Agp1 + off, lA1);
        gl_lds16(Bgp0 + off, lB0);
        gl_lds16(Bgp1 + off, lB1);
        __syncthreads();
        short8 af[4], bfr[4];
#pragma unroll
        for (int i = 0; i < 4; ++i) {
            const int R = wm + 16 * i + ln;
            af[i] = *(const short8*)&As[R * 32 + ((q ^ (R & 3)) * 8)];
        }
#pragma unroll
        for (int j = 0; j < 4; ++j) {
            const int R = wn + 16 * j + ln;
            bfr[j] = *(const short8*)&Bs[R * 32 + ((q ^ (R & 3)) * 8)];
        }
#pragma unroll
        for (int i = 0; i < 4; ++i)
#pragma unroll
            for (int j = 0; j < 4; ++j)
                acc[i][j] = __builtin_amdgcn_mfma_f32_16x16x32_bf16(af[i], bfr[j], acc[i][j], 0, 0, 0);
    }

#pragma unroll
    for (int i = 0; i < 4; ++i) {
#pragma unroll
        for (int r = 0; r < 4; ++r) {
            const int row = m0 + wm + 16 * i + q * 4 + r;
#pragma unroll
            for (int j = 0; j < 4; ++j) {
                const int col = n0 + wn + 16 * j + ln;
                float v = acc[i][j][r];
                const long idx = (long)row * N + col;
                if constexpr (EM == EM_SC) {
                    ((unsigned short*)Cv)[idx] = f2bf(v);
                } else if constexpr (EM == EM_PV) {
                    ((unsigned short*)Cv)[idx] = f2bf(v);
                }
            }
        }
    }
}

// ---------------------------------------------------------------------------
// gemm256 v4 — 256x128 / BK=32 / 4 waves / 2 blocks per CU.
//
// K-tile g (32 cols) computed from buf g&1; 4 phases = 4 C-quadrants, 8 MFMA
// each (one k-step per tile). Reads per wave: P1 a0(4)+b0(2), P2 b1(2),
// P3 a1(4), P4 none. Phase = { stages; reads; BAR; lgkm0+sched_barrier;
// setprio(1); 8 MFMA; setprio(0); [vmcnt(2) at P4]; BAR }.
// Stages (into tile g+1 buf 'nxt' / g+2 buf 'cur'):
//   P1: A(g+1)h1 (2 insts)   P2: B(g+1)h0+h1 (2)   P3: none   P4: A(g+2)h0 (2)
// Deadness (reads drain at their phase's lgkm0; the phase's closing BAR
// globalizes; stage of phase p is issued after phase p-1's closing BAR):
//   A(x) h0/h1 last read at x.P3 -> overwritten at (x+1).P4 / (x+2).P1   OK
//   B(x) h0/h1 last read at x.P2 -> overwritten at (x+1).P2             OK
// Gate at g.P4: per-wave outstanding = P1(2)+P2(2)+P4(2)=6; vmcnt(2) keeps
// P4's own stage in flight and completes A(g+1)h1, B(g+1)h0/h1 (and the older
// A(g+1)h0 from (g-1).P4) -> all of tile g+1 resident before (g+1).P1 reads.
// Youngest gated load has 2 full phases of slack. Never drains to 0 mid-loop.
// LDS swizzle: 16B chunk c of row r stored at c^(r&3) (BK=32 -> 4 chunks);
// gl_lds writes linearly so the GLOBAL source chunk is pre-swizzled; ds_read
// applies the same XOR -> uniform 8 accesses/bank (b128 optimum).
// XCD swizzle: bijective chunked remap (all grids %8 == 0).
// ---------------------------------------------------------------------------
#define BARM()   do { __builtin_amdgcn_s_barrier(); asm volatile("" ::: "memory"); } while (0)
#define LGKM0()  asm volatile("s_waitcnt lgkmcnt(0)" ::: "memory")
#define VMCNT(n) asm volatile("s_waitcnt vmcnt(" #n ")" ::: "memory")
#define SCHEDB() __builtin_amdgcn_sched_barrier(0)
#define PRIO1()  __builtin_amdgcn_s_setprio(1)
#define PRIO0()  __builtin_amdgcn_s_setprio(0)

template<int EM>
__launch_bounds__(256, 2)
__global__ void gemm256(const unsigned short* __restrict__ A,
                        const unsigned short* __restrict__ B,
                        void* __restrict__ Cv, int N, int K,
                        const float* __restrict__ bias,
                        const unsigned short* __restrict__ resid16,
                        unsigned short* __restrict__ outQ,
                        unsigned short* __restrict__ outVt)
{
    __shared__ __align__(16) unsigned short As[2][8192];   // [256][32] per buf
    __shared__ __align__(16) unsigned short Bs[2][4096];   // [128][32] per buf

    // bijective XCD swizzle (nwg % 8 == 0 for all launches of this kernel)
    const int nwg = gridDim.x * gridDim.y;
    int wg = blockIdx.y * gridDim.x + blockIdx.x;
    wg = (wg & 7) * (nwg >> 3) + (wg >> 3);
    const int m0 = (wg % gridDim.x) * 256;
    const int n0 = (wg / gridDim.x) * 128;

    const int t = threadIdx.x;
    const int lane = t & 63, wave = t >> 6;
    const int q = lane >> 4, ln = lane & 15;
    const int wm = wave >> 1, wn = wave & 1;      // 2x2 wave grid, 128x64 out each

    // Staging: one inst covers a [64][32] slab (4 KB). Thread t -> slab row
    // t>>2, global chunk (t&3)^(row&3) (pre-swizzled); LDS linear, wave slice
    // = wave*512 elements (64 lanes x 16B).
    const int srow = t >> 2;
    const int csrcS = ((t & 3) ^ (srow & 3)) * 8;
    const unsigned short* AgS = A + (long)(m0 + srow) * K + csrcS;
    const unsigned short* BgS = B + (long)(n0 + srow) * K + csrcS;
    const int wv512 = wave * 512;

    // ds_read geometry: fragment row R = base+16i+ln, chunk q^(R&3) = q^(ln&3)
    const int aBase = (wm * 128 + ln) * 32;
    const int bBase = (wn * 64 + ln) * 32;
    const int cR = ((q ^ (ln & 3)) * 8);

    floatx4 acc[8][4];
#pragma unroll
    for (int i = 0; i < 8; ++i)
#pragma unroll
        for (int j = 0; j < 4; ++j) acc[i][j] = (floatx4){0.f, 0.f, 0.f, 0.f};

    short8 a[4];           // current A m-group fragments (a0/a1 share regs)
    short8 b0r[2], b1r[2];

#define STAGE_A(buf, kt, h) do { \
    const unsigned short* _g = AgS + (long)((h) * 128) * K + ((long)(kt) << 5); \
    gl_lds16(_g,           &As[buf][(h) * 4096 + wv512]); \
    gl_lds16(_g + 64L * K, &As[buf][(h) * 4096 + 2048 + wv512]); \
} while (0)
#define STAGE_B(buf, kt, h) do { \
    const unsigned short* _g = BgS + (long)((h) * 64) * K + ((long)(kt) << 5); \
    gl_lds16(_g, &Bs[buf][(h) * 2048 + wv512]); \
} while (0)
#define RD_A(sel, mg) { \
    _Pragma("unroll") \
    for (int i = 0; i < 4; ++i) \
        a[i] = *(const short8*)&As[sel][aBase + ((mg) * 64 + 16 * i) * 32 + cR]; }
#define RD_B0(sel) { \
    b0r[0] = *(const short8*)&Bs[sel][bBase + 0 * 32 + cR]; \
    b0r[1] = *(const short8*)&Bs[sel][bBase + 16 * 32 + cR]; }
#define RD_B1(sel) { \
    b1r[0] = *(const short8*)&Bs[sel][bBase + 32 * 32 + cR]; \
    b1r[1] = *(const short8*)&Bs[sel][bBase + 48 * 32 + cR]; }
#define MMQ(mg, br, ng) { \
    _Pragma("unroll") \
    for (int i = 0; i < 4; ++i) \
    _Pragma("unroll") \
    for (int j = 0; j < 2; ++j) \
        acc[(mg)*4+i][(ng)*2+j] = __builtin_amdgcn_mfma_f32_16x16x32_bf16( \
            a[i], br[j], acc[(mg)*4+i][(ng)*2+j], 0, 0, 0); }

    const int NG = K >> 5;   // K-tiles of 32 cols; NG >= 3

    // prologue: tile0 full + A(1)h0; gate tile0 (vmcnt(2) keeps A(1)h0 in flight)
    STAGE_A(0, 0, 0); STAGE_A(0, 0, 1);
    STAGE_B(0, 0, 0); STAGE_B(0, 0, 1);
    STAGE_A(1, 1, 0);
    VMCNT(2); BARM();

    for (int g = 0; g < NG - 2; ++g) {
        const int cur = g & 1, nxt = cur ^ 1;
        // P1: Q00
        STAGE_A(nxt, g + 1, 1);
        RD_A(cur, 0); RD_B0(cur);
        BARM(); LGKM0(); SCHEDB();
        PRIO1(); MMQ(0, b0r, 0); PRIO0();
        BARM();
        // P2: Q01
        STAGE_B(nxt, g + 1, 0); STAGE_B(nxt, g + 1, 1);
        RD_B1(cur);
        BARM(); LGKM0(); SCHEDB();
        PRIO1(); MMQ(0, b1r, 1); PRIO0();
        BARM();
        // P3: Q10
        RD_A(cur, 1);
        BARM(); LGKM0(); SCHEDB();
        PRIO1(); MMQ(1, b0r, 0); PRIO0();
        BARM();
        // P4: Q11 + gate for K-tile g+1
        STAGE_A(cur, g + 2, 0);
        BARM(); SCHEDB();
        PRIO1(); MMQ(1, b1r, 1); PRIO0();
        VMCNT(2); BARM();
    }
    // peel g = NG-2: P4 stage suppressed; gate drains fully
    {
        const int g = NG - 2, cur = g & 1, nxt = cur ^ 1;
        STAGE_A(nxt, g + 1, 1);
        RD_A(cur, 0); RD_B0(cur);
        BARM(); LGKM0(); SCHEDB();
        PRIO1(); MMQ(0, b0r, 0); PRIO0();
        BARM();
        STAGE_B(nxt, g + 1, 0); STAGE_B(nxt, g + 1, 1);
        RD_B1(cur);
        BARM(); LGKM0(); SCHEDB();
        PRIO1(); MMQ(0, b1r, 1); PRIO0();
        BARM();
        RD_A(cur, 1);
        BARM(); LGKM0(); SCHEDB();
        PRIO1(); MMQ(1, b0r, 0); PRIO0();
        BARM();
        SCHEDB();
        PRIO1(); MMQ(1, b1r, 1); PRIO0();
        VMCNT(0); BARM();
    }
    // peel g = NG-1: no stages, no barriers (no writers live)
    {
        const int cur = (NG - 1) & 1;
        RD_A(cur, 0); RD_B0(cur);
        LGKM0(); SCHEDB();
        PRIO1(); MMQ(0, b0r, 0); PRIO0();
        RD_B1(cur);
        LGKM0(); SCHEDB();
        PRIO1(); MMQ(0, b1r, 1); PRIO0();
        RD_A(cur, 1);
        LGKM0(); SCHEDB();
        PRIO1(); MMQ(1, b0r, 0); PRIO0();
        PRIO1(); MMQ(1, b1r, 1); PRIO0();
    }

#undef STAGE_A
#undef STAGE_B
#undef RD_A
#undef RD_B0
#undef RD_B1
#undef MMQ

    // epilogue: within 16x16 tile, row = q*4+reg, col = ln (verified m89/m91)
#pragma unroll
    for (int i = 0; i < 8; ++i) {
#pragma unroll
        for (int r = 0; r < 4; ++r) {
            const int row = m0 + wm * 128 + 16 * i + q * 4 + r;
#pragma unroll
            for (int j = 0; j < 4; ++j) {
                const int col = n0 + wn * 64 + 16 * j + ln;
                float v = acc[i][j][r];
                const long idx = (long)row * N + col;
                if constexpr (EM == EM_QKV) {
                    v += bias[col];
                    const unsigned short vb = f2bf(v);
                    const int p = col >> 11, c2 = col & 2047;
                    if (p == 0)      outQ[(long)row * 2048 + c2] = vb;
                    else if (p == 1) (outQ + PLANE)[(long)row * 2048 + c2] = vb;
                    else             outVt[(long)(row >> 11) * SS + (long)c2 * 2048 + (row & 2047)] = vb;
                } else if constexpr (EM == EM_PROJ) {
                    v += bias[col] + bf2f(resid16[idx]);    // resid = LN1 out (bf16 x1)
                    ((float*)Cv)[idx] = v;
                } else if constexpr (EM == EM_FFN1) {
                    v = fmaxf(v + bias[col], 0.f);
                    ((unsigned short*)Cv)[idx] = f2bf(v);
                } else { // EM_F2A
                    ((float*)Cv)[idx] += v;
                }
            }
        }
    }
}

// rows of length 2048: fp32 (stride srcld) -> bf16 (stride 2048)
__launch_bounds__(256)
__global__ void cvt_rows(const float* __restrict__ src, unsigned short* __restrict__ dst, long srcld)
{
    const int row = blockIdx.x, t = threadIdx.x;
    const float* s = src + (long)row * srcld + t * 8;
    float4 a = *(const float4*)s;
    float4 b = *(const float4*)(s + 4);
    *(uint4*)(dst + (long)row * 2048 + t * 8) = pack8(a, b);
}

// LayerNorm: fp32 in (2048 cols), bf16 out; fp32 gamma/beta.
__launch_bounds__(256)
__global__ void layernorm_k(const float* __restrict__ X, unsigned short* __restrict__ Y,
                            const float* __restrict__ g, const float* __restrict__ be)
{
    const int row = blockIdx.x, t = threadIdx.x;
    const float* Xr = X + (long)row * 2048 + t * 8;
    float4 v0 = *(const float4*)Xr;
    float4 v1 = *(const float4*)(Xr + 4);
    float x[8] = {v0.x, v0.y, v0.z, v0.w, v1.x, v1.y, v1.z, v1.w};
    float s = 0.f, ss = 0.f;
#pragma unroll
    for (int k = 0; k < 8; ++k) { s += x[k]; ss += x[k] * x[k]; }
    for (int off = 32; off; off >>= 1) { s += __shfl_down(s, off, 64); ss += __shfl_down(ss, off, 64); }
    __shared__ float red[8];
    const int wave = t >> 6, lane = t & 63;
    if (lane == 0) { red[wave] = s; red[4 + wave] = ss; }
    __syncthreads();
    s  = red[0] + red[1] + red[2] + red[3];
    ss = red[4] + red[5] + red[6] + red[7];
    const float mean = s * (1.f / 2048.f);
    const float var  = ss * (1.f / 2048.f) - mean * mean;
    const float rstd = rsqrtf(var + 1e-5f);
    unsigned short o[8];
#pragma unroll
    for (int k = 0; k < 8; ++k) {
        const int col = t * 8 + k;
        o[k] = f2bf((x[k] - mean) * rstd * g[col] + be[col]);
    }
    *(uint4*)(Y + (long)row * 2048 + t * 8) = *(uint4*)o;
}

// In-place RoPE on bf16 Q (blockIdx.y=0) / K (=1), replicating the reference quirk:
// emb = concat(sin(sp),cos(sp)); c=cos(emb), s=sin(emb); rh = concat(-x[::2], x[1::2]).
__launch_bounds__(256)
__global__ void rope_inplace(unsigned short* __restrict__ Q, unsigned short* __restrict__ K)
{
    __shared__ __align__(16) unsigned short rowbuf[2048];
    const int row = blockIdx.x;              // 0..8191 (b*2048+p)
    const int mtx = blockIdx.y;
    unsigned short* X = (mtx ? K : Q) + (long)row * 2048;
    const int t = threadIdx.x;
    *(uint4*)&rowbuf[t * 8] = *(const uint4*)(X + t * 8);
    __syncthreads();
    const int p = row & 2047;
    const float sgn = mtx ? -1.f : 1.f;
    unsigned short o[8];
#pragma unroll
    for (int e = 0; e < 8; ++e) {
        const int j = t * 8 + e;
        const int i = j & 1023;
        const float freq = __expf(-(float)i * (9.210340371976184f / 1024.0f)); // 10000^(-i/1024)
        const float sp = (float)p * freq;
        const float emb = (j < 1024) ? sinf(sp) : cosf(sp);
        float se, ce;
        sincosf(emb, &se, &ce);
        const int pj = (j < 1024) ? (2 * j) : (2 * j - 2047);
        float xp = bf2f(rowbuf[pj]);
        if (j < 1024) xp = -xp;
        o[e] = f2bf(bf2f(rowbuf[j]) * ce + sgn * xp * se);
    }
    *(uint4*)(X + t * 8) = *(uint4*)o;
}

// Causal softmax in-place on bf16 scores (2048x2048); full rows written (zeros past edge).
__launch_bounds__(256)
__global__ void softmax_causal(unsigned short* __restrict__ S)
{
    const int qq = blockIdx.x;
    const int L = qq + 1;
    unsigned short* srow = S + (long)qq * 2048;
    const int t = threadIdx.x;
    const float scale = 0.022097086912079608f; // 1/sqrt(2048)
    float vals[8];
    float m = -1e30f;
#pragma unroll
    for (int u = 0; u < 8; ++u) {
        const int i2 = t + 256 * u;
        vals[u] = (i2 < L) ? bf2f(srow[i2]) * scale : -1e30f;
        m = fmaxf(m, vals[u]);
    }
    for (int off = 32; off; off >>= 1) m = fmaxf(m, __shfl_down(m, off, 64));
    __shared__ float red[8];
    const int wave = t >> 6, lane = t & 63;
    if (lane == 0) red[wave] = m;
    __syncthreads();
    m = fmaxf(fmaxf(red[0], red[1]), fmaxf(red[2], red[3]));
    float sum = 0.f;
#pragma unroll
    for (int u = 0; u < 8; ++u) {
        float e = __expf(vals[u] - m);
        e = (t + 256 * u < L) ? e : 0.f;
        vals[u] = e; sum += e;
    }
    for (int off = 32; off; off >>= 1) sum += __shfl_down(sum, off, 64);
    if (lane == 0) red[4 + wave] = sum;
    __syncthreads();
    sum = red[4] + red[5] + red[6] + red[7];
    const float inv = 1.0f / sum;
#pragma unroll
    for (int u = 0; u < 8; ++u) srow[t + 256 * u] = f2bf(vals[u] * inv);
}

// io += b2 (in place on d_out; src2 already holds residual + FFN2 accumulation)
__launch_bounds__(256)
__global__ void final_add(float* __restrict__ io, const float* __restrict__ b2)
{
    const int row = blockIdx.x, t = threadIdx.x;
    const long base = (long)row * 2048 + t * 8;
    float4 a0 = *(const float4*)(io + base);
    float4 a1 = *(const float4*)(io + base + 4);
    float4 c0 = *(const float4*)(b2 + t * 8);
    float4 c1 = *(const float4*)(b2 + t * 8 + 4);
    a0.x += c0.x; a0.y += c0.y; a0.z += c0.z; a0.w += c0.w;
    a1.x += c1.x; a1.y += c1.y; a1.z += c1.z; a1.w += c1.w;
    *(float4*)(io + base) = a0;
    *(float4*)(io + base + 4) = a1;
}

extern "C" void kernel_launch(void* const* d_in, const int* in_sizes, int n_in,
                              void* d_out, int out_size, void* d_ws, size_t ws_size,
                              hipStream_t stream)
{
    const float* src  = (const float*)d_in[0];
    const float* Wqkv = (const float*)d_in[1];
    const float* bqkv = (const float*)d_in[2];
    const float* Wo   = (const float*)d_in[3];
    const float* bo   = (const float*)d_in[4];
    const float* W1   = (const float*)d_in[5];
    const float* b1   = (const float*)d_in[6];
    const float* W2   = (const float*)d_in[7];
    const float* b2   = (const float*)d_in[8];
    const float* g1   = (const float*)d_in[9];
    const float* be1  = (const float*)d_in[10];
    const float* g2   = (const float*)d_in[11];
    const float* be2  = (const float*)d_in[12];

    char* ws = (char*)d_ws;
    const long MB = 1LL << 20;
    unsigned short* x1    = (unsigned short*)ws;                 // w0: LN1 out -> h2
    unsigned short* Vt    = (unsigned short*)(ws + 32 * MB);     // w1: Vt -> f1
    unsigned short* Wqbf  = (unsigned short*)(ws + 64 * MB);     // w2: Wqkv_bf -> attn
    unsigned short* attn  = (unsigned short*)(ws + 64 * MB);
    unsigned short* scP   = (unsigned short*)(ws + 96 * MB);     // w3: bf16 scores/P (8 MiB)
    unsigned short* Wobf  = (unsigned short*)(ws + 96 * MB);     //     -> Wo_bf (8 MiB)
    unsigned short* W1c   = (unsigned short*)(ws + 96 * MB);     //     -> W1 chunk (8 MiB)
    unsigned short* W2c   = (unsigned short*)(ws + 104 * MB);    //     -> W2 chunk (8 MiB)
    unsigned short* h2    = x1;
    unsigned short* f1    = Vt;

    unsigned short* Q    = (unsigned short*)d_out;               // Q [0,32MiB), K [32,64MiB)
    float*          src2 = (float*)d_out;                        // after PROJ (Q,K dead)
    float*          out  = (float*)d_out;

    const dim3 blk(256);

    cvt_rows<<<6144, blk, 0, stream>>>(Wqkv, Wqbf, 2048);
    layernorm_k<<<8192, blk, 0, stream>>>(src, x1, g1, be1);
    gemm256<EM_QKV><<<dim3(32, 48), blk, 0, stream>>>(
        x1, Wqbf, nullptr, 6144, 2048, bqkv, nullptr, Q, Vt);
    rope_inplace<<<dim3(8192, 2), blk, 0, stream>>>(Q, Q + PLANE);

    for (int b = 0; b < 4; ++b) {
        gemm_bt<EM_SC><<<dim3(16, 16), blk, 0, stream>>>(
            Q + b * SS, Q + PLANE + b * SS, scP, 2048, 2048, nullptr, nullptr, nullptr, nullptr);
        softmax_causal<<<2048, blk, 0, stream>>>(scP);
        gemm_bt<EM_PV><<<dim3(16, 16), blk, 0, stream>>>(
            scP, Vt + b * SS, attn + b * SS, 2048, 2048, nullptr, nullptr, nullptr, nullptr);
    }

    cvt_rows<<<2048, blk, 0, stream>>>(Wo, Wobf, 2048);
    gemm256<EM_PROJ><<<dim3(32, 16), blk, 0, stream>>>(
        attn, Wobf, src2, 2048, 2048, bo, x1, nullptr, nullptr);
    layernorm_k<<<8192, blk, 0, stream>>>(src2, h2, g2, be2);

    for (int c = 0; c < 4; ++c) {
        cvt_rows<<<2048, blk, 0, stream>>>(W1 + (long)c * 2048 * 2048, W1c, 2048);
        cvt_rows<<<2048, blk, 0, stream>>>(W2 + (long)c * 2048, W2c, 8192);
        gemm256<EM_FFN1><<<dim3(32, 16), blk, 0, stream>>>(
            h2, W1c, f1, 2048, 2048, b1 + c * 2048, nullptr, nullptr, nullptr);
        gemm256<EM_F2A><<<dim3(32, 16), blk, 0, stream>>>(
            f1, W2c, src2, 2048, 2048, nullptr, nullptr, nullptr, nullptr);
    }
    final_add<<<8192, blk, 0, stream>>>(out, b2);
}

// Round 6
// 1369.648 us; speedup vs baseline: 1.3835x; 1.3835x over previous
//
#include <hip/hip_runtime.h>
#include <cstdint>

// B=4, S=2048, d=2048, dff=8192. Inputs fp32, output fp32.
// All GEMMs bf16 MFMA (fp32 accum). Weights pre-converted fp32->bf16 per phase.
//
// ws (112 MiB): w0[0,32) x1 -> h2 | w1[32,64) Vt -> f1
//               w2[64,96) Wqkv_bf(24) -> attn(32) -> W1bf(32)
//               w3[96,112) scP 2x8MB (pair-batched scores) -> Wo_bf(8) + W2c@[104,112)
// d_out (64 MiB fp32): Q bf16 [0,32MiB) + K bf16 [32,64MiB) until PROJ, then src2 fp32.
//
// gemm256 (QKV/PROJ/FFN1/F2A): R1-exact 256x256/BK=64/8-wave 8-phase kernel
// (best measured: QKV 255us, 0 LDS conflicts). gemm_bt (SC/PV): 128x128/BK=32
// with CORRECTED swizzle h(R)=(R>>1)&3 (old (R&3) gave 2-way b128 conflicts:
// 8-lane service groups hit identical bank quads for ln and ln+4).
// Attention pair-batched via blockIdx.z (2 score buffers) for launch fill.
// (R5 bench was an infra failure — this resubmits the same experiment.)

typedef __attribute__((ext_vector_type(8))) short short8;
typedef __attribute__((ext_vector_type(4))) float floatx4;

#define PLANE 16777216L   // 8192*2048 (Q->K plane stride, elements)
#define SS    4194304L    // 2048*2048 (per-batch matrix, elements)

__device__ __forceinline__ float bf2f(unsigned short u) {
    union { unsigned int i; float f; } v; v.i = ((unsigned int)u) << 16; return v.f;
}
__device__ __forceinline__ unsigned short f2bf(float f) {
    union { float f; unsigned int i; } v; v.f = f;
    unsigned int x = v.i;
    return (unsigned short)((x + 0x7FFFu + ((x >> 16) & 1u)) >> 16);
}
__device__ __forceinline__ uint4 pack8(float4 a, float4 b) {
    unsigned short o[8];
    o[0] = f2bf(a.x); o[1] = f2bf(a.y); o[2] = f2bf(a.z); o[3] = f2bf(a.w);
    o[4] = f2bf(b.x); o[5] = f2bf(b.y); o[6] = f2bf(b.z); o[7] = f2bf(b.w);
    return *(uint4*)o;
}
// async global->LDS, 16B per lane; LDS dest = wave-uniform base + lane*16
__device__ __forceinline__ void gl_lds16(const void* g, void* l) {
    __builtin_amdgcn_global_load_lds(
        (const __attribute__((address_space(1))) void*)g,
        (__attribute__((address_space(3))) void*)l, 16, 0, 0);
}

#define EM_QKV  0
#define EM_SC   1
#define EM_PV   2
#define EM_PROJ 3
#define EM_FFN1 4
#define EM_F2A  5

// ---------------------------------------------------------------------------
// 128x128 kernel for the causal attention GEMMs (SC, PV), pair-batched by
// blockIdx.z (zA/zB/zC = per-z element strides).
// Swizzle: 16B chunk slot c of row r holds global chunk c ^ ((r>>1)&3).
// ds_read chunk = q ^ ((R>>1)&3); an 8-lane b128 service group (rows ln=0..7,
// 64B rows) covers all eight 16B slots of each 128B line bijectively ->
// conflict-free. Staged source is pre-swizzled (global_load_lds is linear).
// ---------------------------------------------------------------------------
template<int EM>
__launch_bounds__(256, 2)
__global__ void gemm_bt(const unsigned short* __restrict__ A,
                        const unsigned short* __restrict__ B,
                        void* __restrict__ Cv, int N, int K,
                        long zA, long zB, long zC)
{
    constexpr int BM = 128, BN = 128, BK = 32;
    __shared__ __align__(16) unsigned short As[BM * BK];
    __shared__ __align__(16) unsigned short Bs[BN * BK];

    const int z = blockIdx.z;
    A += (long)z * zA;
    B += (long)z * zB;
    unsigned short* C16 = (unsigned short*)Cv + (long)z * zC;

    const int m0 = blockIdx.x * BM, n0 = blockIdx.y * BN;
    if (EM == EM_SC && n0 > m0 + (BM - 1)) return;   // fully-masked causal tile

    int kmax = K;
    if (EM == EM_PV) { kmax = m0 + BM; if (kmax > K) kmax = K; }  // P zero past causal edge
    const int nsteps = kmax / BK;

    const int t = threadIdx.x;
    const int lane = t & 63, wave = t >> 6;
    const int q = lane >> 4, ln = lane & 15;
    const int wm = (wave >> 1) * 64, wn = (wave & 1) * 64;

    const int r0 = wave * 32;
    const int rA = r0 + (lane >> 2);
    const int cslot = lane & 3;
    const int cg0 = (cslot ^ ((rA >> 1) & 3)) * 8;            // h(r)=(r>>1)&3
    const int cg1 = (cslot ^ (((rA + 16) >> 1) & 3)) * 8;     // == cg0 (16>>1=8, mod4=0)
    const unsigned short* Agp0 = A + (long)(m0 + rA) * K + cg0;
    const unsigned short* Agp1 = A + (long)(m0 + rA + 16) * K + cg1;
    const unsigned short* Bgp0 = B + (long)(n0 + rA) * K + cg0;
    const unsigned short* Bgp1 = B + (long)(n0 + rA + 16) * K + cg1;
    unsigned short* lA0 = &As[r0 * 32];
    unsigned short* lA1 = &As[(r0 + 16) * 32];
    unsigned short* lB0 = &Bs[r0 * 32];
    unsigned short* lB1 = &Bs[(r0 + 16) * 32];

    floatx4 acc[4][4];
#pragma unroll
    for (int i = 0; i < 4; ++i)
#pragma unroll
        for (int j = 0; j < 4; ++j) acc[i][j] = (floatx4){0.f, 0.f, 0.f, 0.f};

    for (int s = 0; s < nsteps; ++s) {
        const long off = (long)s * BK;
        __syncthreads();
        gl_lds16(Agp0 + off, lA0);
        gl_lds16(Agp1 + off, lA1);
        gl_lds16(Bgp0 + off, lB0);
        gl_lds16(Bgp1 + off, lB1);
        __syncthreads();
        short8 af[4], bfr[4];
#pragma unroll
        for (int i = 0; i < 4; ++i) {
            const int R = wm + 16 * i + ln;
            af[i] = *(const short8*)&As[R * 32 + ((q ^ ((R >> 1) & 3)) * 8)];
        }
#pragma unroll
        for (int j = 0; j < 4; ++j) {
            const int R = wn + 16 * j + ln;
            bfr[j] = *(const short8*)&Bs[R * 32 + ((q ^ ((R >> 1) & 3)) * 8)];
        }
#pragma unroll
        for (int i = 0; i < 4; ++i)
#pragma unroll
            for (int j = 0; j < 4; ++j)
                acc[i][j] = __builtin_amdgcn_mfma_f32_16x16x32_bf16(af[i], bfr[j], acc[i][j], 0, 0, 0);
    }

#pragma unroll
    for (int i = 0; i < 4; ++i) {
#pragma unroll
        for (int r = 0; r < 4; ++r) {
            const int row = m0 + wm + 16 * i + q * 4 + r;
#pragma unroll
            for (int j = 0; j < 4; ++j) {
                const int col = n0 + wn + 16 * j + ln;
                const long idx = (long)row * N + col;
                C16[idx] = f2bf(acc[i][j][r]);
            }
        }
    }
}

// ---------------------------------------------------------------------------
// gemm256 — R1-exact 256x256 / BK=64 / 8-wave / 8-phase counted-vmcnt GEMM.
// (Best measured variant: QKV 255us, MfmaUtil 35.5%, 0 bank conflicts.)
// ---------------------------------------------------------------------------
#define BAR()    __builtin_amdgcn_s_barrier()
#define LGKM0()  asm volatile("s_waitcnt lgkmcnt(0)" ::: "memory")
#define VMCNT(n) asm volatile("s_waitcnt vmcnt(" #n ")" ::: "memory")

template<int EM>
__launch_bounds__(512, 2)
__global__ void gemm256(const unsigned short* __restrict__ A,
                        const unsigned short* __restrict__ B,
                        void* __restrict__ Cv, int N, int K,
                        const float* __restrict__ bias,
                        const unsigned short* __restrict__ resid16,
                        unsigned short* __restrict__ outQ,
                        unsigned short* __restrict__ outVt)
{
    __shared__ __align__(16) unsigned short As[2][16384];
    __shared__ __align__(16) unsigned short Bs[2][16384];

    const int m0 = blockIdx.x * 256, n0 = blockIdx.y * 256;
    const int t = threadIdx.x;
    const int lane = t & 63, wave = t >> 6;
    const int q = lane >> 4, ln = lane & 15;
    const int wm = wave >> 2, wn = wave & 3;      // 2 x 4 wave grid, 128x64 out each

    const int jrow = lane >> 3;
    const int csrc = ((lane & 7) ^ jrow) * 8;
    const unsigned short* Ag = A + (long)(m0 + wave * 16 + jrow) * K + csrc;
    const unsigned short* Bg = B + (long)(n0 + wave * 16 + jrow) * K + csrc;
    const int ldsSlice = wave * 1024;             // elements; +512 for inst 1

    const int aBase = (wm * 128 + ln) * 64;
    const int bBase = (wn * 64 + ln) * 64;
    const int c0 = ((0 + q) ^ (ln & 7)) * 8;
    const int c1 = ((4 + q) ^ (ln & 7)) * 8;

    floatx4 acc[8][4];
#pragma unroll
    for (int i = 0; i < 8; ++i)
#pragma unroll
        for (int j = 0; j < 4; ++j) acc[i][j] = (floatx4){0.f, 0.f, 0.f, 0.f};

    short8 a[4][2];        // current m-group frags (4 frags x 2 ksteps)
    short8 b[2][2][2];     // [ngroup][frag][kstep]

#define STAGE_A(buf, kt, h) do { \
    const unsigned short* _g = Ag + (long)((h) * 128) * K + ((long)(kt) << 6); \
    gl_lds16(_g,          &As[buf][(h) * 8192 + ldsSlice]); \
    gl_lds16(_g + 8L * K, &As[buf][(h) * 8192 + ldsSlice + 512]); \
} while (0)
#define STAGE_B(buf, kt, h) do { \
    const unsigned short* _g = Bg + (long)((h) * 128) * K + ((long)(kt) << 6); \
    gl_lds16(_g,          &Bs[buf][(h) * 8192 + ldsSlice]); \
    gl_lds16(_g + 8L * K, &Bs[buf][(h) * 8192 + ldsSlice + 512]); \
} while (0)
#define RD_A(sel, mg) { \
    _Pragma("unroll") \
    for (int i = 0; i < 4; ++i) { \
        a[i][0] = *(const short8*)&As[sel][aBase + ((mg) * 64 + 16 * i) * 64 + c0]; \
        a[i][1] = *(const short8*)&As[sel][aBase + ((mg) * 64 + 16 * i) * 64 + c1]; \
    } }
#define RD_B(sel, ng) { \
    _Pragma("unroll") \
    for (int j = 0; j < 2; ++j) { \
        b[ng][j][0] = *(const short8*)&Bs[sel][bBase + ((ng) * 32 + 16 * j) * 64 + c0]; \
        b[ng][j][1] = *(const short8*)&Bs[sel][bBase + ((ng) * 32 + 16 * j) * 64 + c1]; \
    } }
#define MM(mg, ng) { \
    _Pragma("unroll") \
    for (int i = 0; i < 4; ++i) \
    _Pragma("unroll") \
    for (int j = 0; j < 2; ++j) { \
        acc[(mg)*4+i][(ng)*2+j] = __builtin_amdgcn_mfma_f32_16x16x32_bf16( \
            a[i][0], b[ng][j][0], acc[(mg)*4+i][(ng)*2+j], 0, 0, 0); \
        acc[(mg)*4+i][(ng)*2+j] = __builtin_amdgcn_mfma_f32_16x16x32_bf16( \
            a[i][1], b[ng][j][1], acc[(mg)*4+i][(ng)*2+j], 0, 0, 0); \
    } }

    const int nIter = K >> 7;   // 128 K-columns per iteration; K % 128 == 0

    // prologue: A(0),B(0) -> buf0; B(1) -> buf1; allow B(1) in flight
    STAGE_A(0, 0, 0); STAGE_A(0, 0, 1);
    STAGE_B(0, 0, 0); STAGE_B(0, 0, 1);
    STAGE_B(1, 1, 0); STAGE_B(1, 1, 1);
    VMCNT(4); BAR();

    for (int it = 0; it < nIter - 1; ++it) {
        const int k1 = 2 * it + 1, ke = 2 * it + 2, ko = 2 * it + 3;
        // P1
        RD_A(0, 0); RD_B(0, 0);
        STAGE_A(1, k1, 0);
        BAR(); LGKM0();
        __builtin_amdgcn_s_setprio(1); MM(0, 0); __builtin_amdgcn_s_setprio(0);
        BAR();
        // P2
        RD_B(0, 1);
        STAGE_A(1, k1, 1);
        BAR(); LGKM0();
        __builtin_amdgcn_s_setprio(1); MM(0, 1); __builtin_amdgcn_s_setprio(0);
        BAR();
        // P3
        RD_A(0, 1);
        STAGE_B(0, ke, 0);
        BAR(); LGKM0();
        __builtin_amdgcn_s_setprio(1); MM(1, 0); __builtin_amdgcn_s_setprio(0);
        BAR();
        // P4 + gate for buf1
        STAGE_B(0, ke, 1);
        BAR();
        __builtin_amdgcn_s_setprio(1); MM(1, 1); __builtin_amdgcn_s_setprio(0);
        VMCNT(4); BAR();
        // P5
        RD_A(1, 0); RD_B(1, 0);
        STAGE_A(0, ke, 0);
        BAR(); LGKM0();
        __builtin_amdgcn_s_setprio(1); MM(0, 0); __builtin_amdgcn_s_setprio(0);
        BAR();
        // P6
        RD_B(1, 1);
        STAGE_A(0, ke, 1);
        BAR(); LGKM0();
        __builtin_amdgcn_s_setprio(1); MM(0, 1); __builtin_amdgcn_s_setprio(0);
        BAR();
        // P7
        RD_A(1, 1);
        STAGE_B(1, ko, 0);
        BAR(); LGKM0();
        __builtin_amdgcn_s_setprio(1); MM(1, 0); __builtin_amdgcn_s_setprio(0);
        BAR();
        // P8 + gate for buf0
        STAGE_B(1, ko, 1);
        BAR();
        __builtin_amdgcn_s_setprio(1); MM(1, 1); __builtin_amdgcn_s_setprio(0);
        VMCNT(4); BAR();
    }

    // peel: K-tiles nk-2 (buf0) and nk-1 (buf1); only A(nk-1) left to stage
    {
        const int k1 = 2 * nIter - 1;
        RD_A(0, 0); RD_B(0, 0);
        STAGE_A(1, k1, 0);
        BAR(); LGKM0();
        __builtin_amdgcn_s_setprio(1); MM(0, 0); __builtin_amdgcn_s_setprio(0);
        BAR();
        RD_B(0, 1);
        STAGE_A(1, k1, 1);
        BAR(); LGKM0();
        __builtin_amdgcn_s_setprio(1); MM(0, 1); __builtin_amdgcn_s_setprio(0);
        BAR();
        RD_A(0, 1);
        BAR(); LGKM0();
        __builtin_amdgcn_s_setprio(1); MM(1, 0); __builtin_amdgcn_s_setprio(0);
        BAR();
        __builtin_amdgcn_s_setprio(1); MM(1, 1); __builtin_amdgcn_s_setprio(0);
        VMCNT(0); BAR();
        // tail K-tile from buf1: no stages, no barriers needed
        RD_A(1, 0); RD_B(1, 0);
        MM(0, 0);
        RD_B(1, 1);
        MM(0, 1);
        RD_A(1, 1);
        MM(1, 0); MM(1, 1);
    }

#undef STAGE_A
#undef STAGE_B
#undef RD_A
#undef RD_B
#undef MM

    // epilogue: within 16x16 tile, row = q*4+reg, col = ln (verified m89/m91)
#pragma unroll
    for (int i = 0; i < 8; ++i) {
#pragma unroll
        for (int r = 0; r < 4; ++r) {
            const int row = m0 + wm * 128 + 16 * i + q * 4 + r;
#pragma unroll
            for (int j = 0; j < 4; ++j) {
                const int col = n0 + wn * 64 + 16 * j + ln;
                float v = acc[i][j][r];
                const long idx = (long)row * N + col;
                if constexpr (EM == EM_QKV) {
                    v += bias[col];
                    const unsigned short vb = f2bf(v);
                    const int p = col >> 11, c2 = col & 2047;
                    if (p == 0)      outQ[(long)row * 2048 + c2] = vb;
                    else if (p == 1) (outQ + PLANE)[(long)row * 2048 + c2] = vb;
                    else             outVt[(long)(row >> 11) * SS + (long)c2 * 2048 + (row & 2047)] = vb;
                } else if constexpr (EM == EM_PROJ) {
                    v += bias[col] + bf2f(resid16[idx]);    // resid = LN1 out (bf16 x1)
                    ((float*)Cv)[idx] = v;
                } else if constexpr (EM == EM_FFN1) {
                    v = fmaxf(v + bias[col], 0.f);
                    ((unsigned short*)Cv)[idx] = f2bf(v);
                } else { // EM_F2A
                    ((float*)Cv)[idx] += v;
                }
            }
        }
    }
}

// rows of length 2048: fp32 (stride srcld) -> bf16 (stride 2048)
__launch_bounds__(256)
__global__ void cvt_rows(const float* __restrict__ src, unsigned short* __restrict__ dst, long srcld)
{
    const int row = blockIdx.x, t = threadIdx.x;
    const float* s = src + (long)row * srcld + t * 8;
    float4 a = *(const float4*)s;
    float4 b = *(const float4*)(s + 4);
    *(uint4*)(dst + (long)row * 2048 + t * 8) = pack8(a, b);
}

// LayerNorm: fp32 in (2048 cols), bf16 out; fp32 gamma/beta.
__launch_bounds__(256)
__global__ void layernorm_k(const float* __restrict__ X, unsigned short* __restrict__ Y,
                            const float* __restrict__ g, const float* __restrict__ be)
{
    const int row = blockIdx.x, t = threadIdx.x;
    const float* Xr = X + (long)row * 2048 + t * 8;
    float4 v0 = *(const float4*)Xr;
    float4 v1 = *(const float4*)(Xr + 4);
    float x[8] = {v0.x, v0.y, v0.z, v0.w, v1.x, v1.y, v1.z, v1.w};
    float s = 0.f, ss = 0.f;
#pragma unroll
    for (int k = 0; k < 8; ++k) { s += x[k]; ss += x[k] * x[k]; }
    for (int off = 32; off; off >>= 1) { s += __shfl_down(s, off, 64); ss += __shfl_down(ss, off, 64); }
    __shared__ float red[8];
    const int wave = t >> 6, lane = t & 63;
    if (lane == 0) { red[wave] = s; red[4 + wave] = ss; }
    __syncthreads();
    s  = red[0] + red[1] + red[2] + red[3];
    ss = red[4] + red[5] + red[6] + red[7];
    const float mean = s * (1.f / 2048.f);
    const float var  = ss * (1.f / 2048.f) - mean * mean;
    const float rstd = rsqrtf(var + 1e-5f);
    unsigned short o[8];
#pragma unroll
    for (int k = 0; k < 8; ++k) {
        const int col = t * 8 + k;
        o[k] = f2bf((x[k] - mean) * rstd * g[col] + be[col]);
    }
    *(uint4*)(Y + (long)row * 2048 + t * 8) = *(uint4*)o;
}

// In-place RoPE on bf16 Q (blockIdx.y=0) / K (=1), replicating the reference quirk:
// emb = concat(sin(sp),cos(sp)); c=cos(emb), s=sin(emb); rh = concat(-x[::2], x[1::2]).
__launch_bounds__(256)
__global__ void rope_inplace(unsigned short* __restrict__ Q, unsigned short* __restrict__ K)
{
    __shared__ __align__(16) unsigned short rowbuf[2048];
    const int row = blockIdx.x;              // 0..8191 (b*2048+p)
    const int mtx = blockIdx.y;
    unsigned short* X = (mtx ? K : Q) + (long)row * 2048;
    const int t = threadIdx.x;
    *(uint4*)&rowbuf[t * 8] = *(const uint4*)(X + t * 8);
    __syncthreads();
    const int p = row & 2047;
    const float sgn = mtx ? -1.f : 1.f;
    unsigned short o[8];
#pragma unroll
    for (int e = 0; e < 8; ++e) {
        const int j = t * 8 + e;
        const int i = j & 1023;
        const float freq = __expf(-(float)i * (9.210340371976184f / 1024.0f)); // 10000^(-i/1024)
        const float sp = (float)p * freq;
        const float emb = (j < 1024) ? sinf(sp) : cosf(sp);
        float se, ce;
        sincosf(emb, &se, &ce);
        const int pj = (j < 1024) ? (2 * j) : (2 * j - 2047);
        float xp = bf2f(rowbuf[pj]);
        if (j < 1024) xp = -xp;
        o[e] = f2bf(bf2f(rowbuf[j]) * ce + sgn * xp * se);
    }
    *(uint4*)(X + t * 8) = *(uint4*)o;
}

// Causal softmax in-place on bf16 scores; blockIdx.y = batch slot (stride SS).
__launch_bounds__(256)
__global__ void softmax_causal(unsigned short* __restrict__ S)
{
    const int qq = blockIdx.x;
    const int L = qq + 1;
    unsigned short* srow = S + (long)blockIdx.y * SS + (long)qq * 2048;
    const int t = threadIdx.x;
    const float scale = 0.022097086912079608f; // 1/sqrt(2048)
    float vals[8];
    float m = -1e30f;
#pragma unroll
    for (int u = 0; u < 8; ++u) {
        const int i2 = t + 256 * u;
        vals[u] = (i2 < L) ? bf2f(srow[i2]) * scale : -1e30f;
        m = fmaxf(m, vals[u]);
    }
    for (int off = 32; off; off >>= 1) m = fmaxf(m, __shfl_down(m, off, 64));
    __shared__ float red[8];
    const int wave = t >> 6, lane = t & 63;
    if (lane == 0) red[wave] = m;
    __syncthreads();
    m = fmaxf(fmaxf(red[0], red[1]), fmaxf(red[2], red[3]));
    float sum = 0.f;
#pragma unroll
    for (int u = 0; u < 8; ++u) {
        float e = __expf(vals[u] - m);
        e = (t + 256 * u < L) ? e : 0.f;
        vals[u] = e; sum += e;
    }
    for (int off = 32; off; off >>= 1) sum += __shfl_down(sum, off, 64);
    if (lane == 0) red[4 + wave] = sum;
    __syncthreads();
    sum = red[4] + red[5] + red[6] + red[7];
    const float inv = 1.0f / sum;
#pragma unroll
    for (int u = 0; u < 8; ++u) srow[t + 256 * u] = f2bf(vals[u] * inv);
}

// io += b2 (in place on d_out; src2 already holds residual + FFN2 accumulation)
__launch_bounds__(256)
__global__ void final_add(float* __restrict__ io, const float* __restrict__ b2)
{
    const int row = blockIdx.x, t = threadIdx.x;
    const long base = (long)row * 2048 + t * 8;
    float4 a0 = *(const float4*)(io + base);
    float4 a1 = *(const float4*)(io + base + 4);
    float4 c0 = *(const float4*)(b2 + t * 8);
    float4 c1 = *(const float4*)(b2 + t * 8 + 4);
    a0.x += c0.x; a0.y += c0.y; a0.z += c0.z; a0.w += c0.w;
    a1.x += c1.x; a1.y += c1.y; a1.z += c1.z; a1.w += c1.w;
    *(float4*)(io + base) = a0;
    *(float4*)(io + base + 4) = a1;
}

extern "C" void kernel_launch(void* const* d_in, const int* in_sizes, int n_in,
                              void* d_out, int out_size, void* d_ws, size_t ws_size,
                              hipStream_t stream)
{
    const float* src  = (const float*)d_in[0];
    const float* Wqkv = (const float*)d_in[1];
    const float* bqkv = (const float*)d_in[2];
    const float* Wo   = (const float*)d_in[3];
    const float* bo   = (const float*)d_in[4];
    const float* W1   = (const float*)d_in[5];
    const float* b1   = (const float*)d_in[6];
    const float* W2   = (const float*)d_in[7];
    const float* b2   = (const float*)d_in[8];
    const float* g1   = (const float*)d_in[9];
    const float* be1  = (const float*)d_in[10];
    const float* g2   = (const float*)d_in[11];
    const float* be2  = (const float*)d_in[12];

    char* ws = (char*)d_ws;
    const long MB = 1LL << 20;
    unsigned short* x1    = (unsigned short*)ws;                 // w0: LN1 out -> h2
    unsigned short* Vt    = (unsigned short*)(ws + 32 * MB);     // w1: Vt -> f1
    unsigned short* Wqbf  = (unsigned short*)(ws + 64 * MB);     // w2: Wqkv_bf -> attn -> W1bf
    unsigned short* attn  = (unsigned short*)(ws + 64 * MB);
    unsigned short* W1bf  = (unsigned short*)(ws + 64 * MB);
    unsigned short* scP   = (unsigned short*)(ws + 96 * MB);     // w3: 2x8MB scores
    unsigned short* Wobf  = (unsigned short*)(ws + 96 * MB);     //     -> Wo_bf (8 MiB)
    unsigned short* W2c   = (unsigned short*)(ws + 104 * MB);    //     W2 chunk (8 MiB)
    unsigned short* h2    = x1;
    unsigned short* f1    = Vt;

    unsigned short* Q    = (unsigned short*)d_out;               // Q [0,32MiB), K [32,64MiB)
    float*          src2 = (float*)d_out;                        // after PROJ (Q,K dead)
    float*          out  = (float*)d_out;

    const dim3 blk(256);
    const dim3 blk512(512);

    cvt_rows<<<6144, blk, 0, stream>>>(Wqkv, Wqbf, 2048);
    layernorm_k<<<8192, blk, 0, stream>>>(src, x1, g1, be1);
    gemm256<EM_QKV><<<dim3(32, 24), blk512, 0, stream>>>(
        x1, Wqbf, nullptr, 6144, 2048, bqkv, nullptr, Q, Vt);
    rope_inplace<<<dim3(8192, 2), blk, 0, stream>>>(Q, Q + PLANE);

    for (int p = 0; p < 2; ++p) {                 // pairs of batches via blockIdx.z
        const long b0 = 2L * p;
        gemm_bt<EM_SC><<<dim3(16, 16, 2), blk, 0, stream>>>(
            Q + b0 * SS, Q + PLANE + b0 * SS, scP, 2048, 2048, SS, SS, SS);
        softmax_causal<<<dim3(2048, 2), blk, 0, stream>>>(scP);
        gemm_bt<EM_PV><<<dim3(16, 16, 2), blk, 0, stream>>>(
            scP, Vt + b0 * SS, attn + b0 * SS, 2048, 2048, SS, SS, SS);
    }

    cvt_rows<<<2048, blk, 0, stream>>>(Wo, Wobf, 2048);
    gemm256<EM_PROJ><<<dim3(32, 8), blk512, 0, stream>>>(
        attn, Wobf, src2, 2048, 2048, bo, x1, nullptr, nullptr);
    layernorm_k<<<8192, blk, 0, stream>>>(src2, h2, g2, be2);

    // full W1 -> bf16 once (attn region dead after PROJ)
    cvt_rows<<<8192, blk, 0, stream>>>(W1, W1bf, 2048);
    for (int c = 0; c < 4; ++c) {
        cvt_rows<<<2048, blk, 0, stream>>>(W2 + (long)c * 2048, W2c, 8192);
        gemm256<EM_FFN1><<<dim3(32, 8), blk512, 0, stream>>>(
            h2, W1bf + (long)c * SS, f1, 2048, 2048, b1 + c * 2048, nullptr, nullptr, nullptr);
        gemm256<EM_F2A><<<dim3(32, 8), blk512, 0, stream>>>(
            f1, W2c, src2, 2048, 2048, nullptr, nullptr, nullptr, nullptr);
    }
    final_add<<<8192, blk, 0, stream>>>(out, b2);
}